// Round 9
// baseline (327.447 us; speedup 1.0000x reference)
//
#include <hip/hip_runtime.h>

// Problem constants
#define TT 8
#define WQ 75
#define CC 64
#define HW 441
#define WAY 5
#define SHOT 5
#define NSAMP 2205     // SHOT*HW
#define NEG 0.2f
#define PPAD 448

typedef __attribute__((ext_vector_type(8))) short bf16x8;
typedef __attribute__((ext_vector_type(4))) float f32x4;

__device__ inline unsigned short f2bf(float f) {
    unsigned u = __float_as_uint(f);
    u += 0x7FFFu + ((u >> 16) & 1u);
    return (unsigned short)(u >> 16);
}
__device__ inline float bf2f(unsigned us) {
    return __uint_as_float((us & 0xFFFFu) << 16);
}

// ---------------------------------------------------------------------------
// k_prep: role-branched.
//  blocks 0..399   : partial second moment G = X X^T + column sums (verified)
//  blocks 400..999 : per-(t,qi) mean -> centered Q -> bf16 hi/lo split S in
//                    [pos][ch] layout (split done ONCE per (t,qi))
// ---------------------------------------------------------------------------
__global__ __launch_bounds__(256) void k_prep(const float* __restrict__ sup,
                                              const float* __restrict__ Q,
                                              float* __restrict__ pG,
                                              float* __restrict__ pS,
                                              unsigned short* __restrict__ Sh,
                                              unsigned short* __restrict__ Sl) {
    const int tid = threadIdx.x;

    if (blockIdx.x < 400) {
        // ---------------- partial covariance role ----------------
        const int blk = blockIdx.x;
        const int half = blk & 1;
        const int b = blk >> 1;                  // t*25 + s
        const float* __restrict__ X = sup + (size_t)b * CC * HW;
        __shared__ float lds[32 * 68];
        const int i = tid & 15;
        const int j = tid >> 4;
        const int c0 = half * 7, c1 = c0 + 7;

        float acc[4][4];
#pragma unroll
        for (int a = 0; a < 4; ++a)
#pragma unroll
            for (int bb = 0; bb < 4; ++bb) acc[a][bb] = 0.f;
        float cs = 0.f;

        float ld[8];
#pragma unroll
        for (int k = 0; k < 8; ++k) {
            const int e = tid + k * 256;
            const int r = e >> 5, pp = e & 31;
            const int p = c0 * 32 + pp;
            ld[k] = (p < HW) ? X[r * HW + p] : 0.f;
        }

        for (int chunk = c0; chunk < c1; ++chunk) {
            __syncthreads();
#pragma unroll
            for (int k = 0; k < 8; ++k) {
                const int e = tid + k * 256;
                const int r = e >> 5, pp = e & 31;
                lds[pp * 68 + r] = ld[k];
            }
            float ld2[8];
            if (chunk + 1 < c1) {
                const int p0 = (chunk + 1) * 32;
#pragma unroll
                for (int k = 0; k < 8; ++k) {
                    const int e = tid + k * 256;
                    const int r = e >> 5, pp = e & 31;
                    const int p = p0 + pp;
                    ld2[k] = (p < HW) ? X[r * HW + p] : 0.f;
                }
            } else {
#pragma unroll
                for (int k = 0; k < 8; ++k) ld2[k] = 0.f;
            }
            __syncthreads();
#pragma unroll 4
            for (int pp = 0; pp < 32; ++pp) {
                const float* row = &lds[pp * 68];
                const float a0 = row[4 * i + 0], a1 = row[4 * i + 1],
                            a2 = row[4 * i + 2], a3 = row[4 * i + 3];
                const float b0 = row[4 * j + 0], b1 = row[4 * j + 1],
                            b2 = row[4 * j + 2], b3 = row[4 * j + 3];
                acc[0][0] += a0 * b0; acc[0][1] += a0 * b1; acc[0][2] += a0 * b2; acc[0][3] += a0 * b3;
                acc[1][0] += a1 * b0; acc[1][1] += a1 * b1; acc[1][2] += a1 * b2; acc[1][3] += a1 * b3;
                acc[2][0] += a2 * b0; acc[2][1] += a2 * b1; acc[2][2] += a2 * b2; acc[2][3] += a2 * b3;
                acc[3][0] += a3 * b0; acc[3][1] += a3 * b1; acc[3][2] += a3 * b2; acc[3][3] += a3 * b3;
            }
            if (tid < CC) {
#pragma unroll 8
                for (int pp = 0; pp < 32; ++pp) cs += lds[pp * 68 + tid];
            }
#pragma unroll
            for (int k = 0; k < 8; ++k) ld[k] = ld2[k];
        }

        float* __restrict__ G = pG + (size_t)blk * 4096;
#pragma unroll
        for (int a = 0; a < 4; ++a)
#pragma unroll
            for (int bb = 0; bb < 4; ++bb)
                G[(4 * i + a) * 64 + (4 * j + bb)] = acc[a][bb];
        if (tid < CC) pS[blk * 64 + tid] = cs;
    } else {
        // ---------------- center + split role ----------------
        const int b = blockIdx.x - 400;          // t*75 + qi
        const float* __restrict__ Qb = Q + (size_t)b * CC * HW;
        __shared__ float part[CC][4];
        __shared__ float muL[CC];

        // pass 1: per-channel mean via float4 loads along p
        {
            const int c = tid >> 2, qtr = tid & 3;
            float s = 0.f;
            for (int p = qtr * 4; p + 3 < HW; p += 16) {
                const float4 v = *(const float4*)(Qb + (size_t)c * HW + p);
                s += (v.x + v.y) + (v.z + v.w);
            }
            if (qtr == 0) s += Qb[(size_t)c * HW + (HW - 1)];   // element 440
            part[c][qtr] = s;
        }
        __syncthreads();
        if (tid < CC)
            muL[tid] = (part[tid][0] + part[tid][1] + part[tid][2] + part[tid][3]) * (1.f / HW);
        __syncthreads();

        // pass 2: p = tid (+256); center, split hi/lo, store transposed
        for (int pi = 0; pi < 2; ++pi) {
            const int p = tid + pi * 256;
            if (p >= PPAD) continue;
            const bool pv = (p < HW);
            const size_t obase = ((size_t)b * PPAD + p) * CC;
#pragma unroll
            for (int o = 0; o < 8; ++o) {
                unsigned hp[4], lp[4];
#pragma unroll
                for (int jj = 0; jj < 4; ++jj) {
                    const int cA = o * 8 + jj * 2;
                    const float v0 = pv ? (Qb[(size_t)cA * HW + p] - muL[cA]) : 0.f;
                    const float v1 = pv ? (Qb[(size_t)(cA + 1) * HW + p] - muL[cA + 1]) : 0.f;
                    const unsigned short h0 = f2bf(v0), h1 = f2bf(v1);
                    const unsigned short l0 = f2bf(v0 - bf2f(h0));
                    const unsigned short l1 = f2bf(v1 - bf2f(h1));
                    hp[jj] = (unsigned)h0 | ((unsigned)h1 << 16);
                    lp[jj] = (unsigned)l0 | ((unsigned)l1 << 16);
                }
                *(uint4*)(Sh + obase + o * 8) = make_uint4(hp[0], hp[1], hp[2], hp[3]);
                *(uint4*)(Sl + obase + o * 8) = make_uint4(lp[0], lp[1], lp[2], lp[3]);
            }
        }
    }
}

// ---------------------------------------------------------------------------
// k_finalize: reduce 10 partials -> covariance -> bf16 hi/lo W.
// 320 blocks ((t*5+way)*8 + idx-chunk), 256 threads, 2 idx each.
// ---------------------------------------------------------------------------
__global__ __launch_bounds__(256) void k_finalize(const float* __restrict__ pG,
                                                  const float* __restrict__ pS,
                                                  unsigned short* __restrict__ Wh,
                                                  unsigned short* __restrict__ Wl) {
    const int blk = blockIdx.x;
    const int b = blk >> 3;                      // t*5 + way
    const int chunk = blk & 7;
    const int t = b / WAY, way = b % WAY;
    const int s0 = (t * 25 + way * SHOT) * 2;

#pragma unroll
    for (int it = 0; it < 2; ++it) {
        const int idx = chunk * 512 + it * 256 + threadIdx.x;
        const int c = idx >> 6, d = idx & 63;
        float g = 0.f, Sc = 0.f, Sd = 0.f;
#pragma unroll
        for (int s = 0; s < SHOT * 2; ++s) {
            g  += pG[(size_t)(s0 + s) * 4096 + idx];
            Sc += pS[(s0 + s) * 64 + c];
            Sd += pS[(s0 + s) * 64 + d];
        }
        const float cov = (g - Sc * Sd * (1.f / NSAMP)) * (1.f / (HW - 1));
        const unsigned short hi = f2bf(cov);
        const unsigned short lo = f2bf(cov - bf2f(hi));
        Wh[(size_t)b * 4096 + idx] = hi;
        Wl[(size_t)b * 4096 + idx] = lo;
    }
}

// ---------------------------------------------------------------------------
// k_sim v7: one (t,qi,way) per block, 4 waves, 7 p-tiles/wave. A-frags (W)
// loaded once; B-frags are clean uint4 loads from staged Sh/Sl (12 VMEM per
// tile total, no f2bf in the loop). Exact-f32 epilogue from hi+lo.
// blockIdx decode keeps a (t,qi)'s 5 way-blocks temporally adjacent for L2
// reuse of the S slice.
// ---------------------------------------------------------------------------
__global__ __launch_bounds__(256) void k_sim(const unsigned short* __restrict__ Sh,
                                             const unsigned short* __restrict__ Sl,
                                             const unsigned short* __restrict__ Wh,
                                             const unsigned short* __restrict__ Wl,
                                             const float* __restrict__ cw,
                                             const float* __restrict__ cb,
                                             float* __restrict__ out) {
    const int gid = blockIdx.x;                  // 0..2999
    const int grp = gid / 40, rem = gid % 40;
    const int w = rem >> 3;                      // 0..4
    const int b = grp * 8 + (rem & 7);           // t*75 + qi
    const int t = b / WQ;
    const int tid = threadIdx.x;
    const int lane = tid & 63;
    const int wid = tid >> 6;                    // 0..3
    const int lm16 = lane & 15;
    const int l16 = lane >> 4;                   // 0..3
    const float lanemask = (l16 == 0) ? 1.f : 0.f;

    __shared__ float fin[4];

    // A-frags: W[row = rt*16 + lm16][k = ks*32 + 8*l16 + i]
    const unsigned short* __restrict__ Wm_h = Wh + (size_t)(t * WAY + w) * 4096;
    const unsigned short* __restrict__ Wm_l = Wl + (size_t)(t * WAY + w) * 4096;
    bf16x8 ah[4][2], al[4][2];
#pragma unroll
    for (int rt = 0; rt < 4; ++rt)
#pragma unroll
        for (int ks = 0; ks < 2; ++ks) {
            const size_t off = (size_t)(rt * 16 + lm16) * 64 + ks * 32 + 8 * l16;
            ah[rt][ks] = __builtin_bit_cast(bf16x8, *(const uint4*)(Wm_h + off));
            al[rt][ks] = __builtin_bit_cast(bf16x8, *(const uint4*)(Wm_l + off));
        }

    const size_t sbase = (size_t)b * PPAD * CC;

    float wayacc = 0.f;
#pragma unroll 1
    for (int k = 0; k < 7; ++k) {
        const int p_l = (wid + 4 * k) * 16 + lm16;
        const size_t prow = sbase + (size_t)p_l * CC;

        // B-frags: 4 uint4 loads
        bf16x8 bh[2], bl[2];
#pragma unroll
        for (int ks = 0; ks < 2; ++ks) {
            const size_t off = prow + ks * 32 + 8 * l16;
            bh[ks] = __builtin_bit_cast(bf16x8, *(const uint4*)(Sh + off));
            bl[ks] = __builtin_bit_cast(bf16x8, *(const uint4*)(Sl + off));
        }

        f32x4 acc[4];
#pragma unroll
        for (int rt = 0; rt < 4; ++rt) acc[rt] = (f32x4){0.f, 0.f, 0.f, 0.f};

#pragma unroll
        for (int rt = 0; rt < 4; ++rt)
#pragma unroll
            for (int ks = 0; ks < 2; ++ks) {
                acc[rt] = __builtin_amdgcn_mfma_f32_16x16x32_bf16(ah[rt][ks], bh[ks], acc[rt], 0, 0, 0);
                acc[rt] = __builtin_amdgcn_mfma_f32_16x16x32_bf16(ah[rt][ks], bl[ks], acc[rt], 0, 0, 0);
                acc[rt] = __builtin_amdgcn_mfma_f32_16x16x32_bf16(al[rt][ks], bh[ks], acc[rt], 0, 0, 0);
            }

        // epilogue: simp = sum over lane's 16 c's of S[c][p]*M[c][p],
        // c = rt*16 + l16*4 + r (m89 C/D layout); S exact = hi + lo.
        float simp = 0.f;
#pragma unroll
        for (int rt = 0; rt < 4; ++rt) {
            const size_t sb = prow + rt * 16 + l16 * 4;
            const uint2 hr = *(const uint2*)(Sh + sb);
            const uint2 lr = *(const uint2*)(Sl + sb);
            simp += acc[rt][0] * (bf2f(hr.x) + bf2f(lr.x));
            simp += acc[rt][1] * (bf2f(hr.x >> 16) + bf2f(lr.x >> 16));
            simp += acc[rt][2] * (bf2f(hr.y) + bf2f(lr.y));
            simp += acc[rt][3] * (bf2f(hr.y >> 16) + bf2f(lr.y >> 16));
        }
        simp += __shfl_xor(simp, 16, 64);
        simp += __shfl_xor(simp, 32, 64);

        const float cwv = (p_l < HW) ? cw[p_l] : 0.f;   // padded p: simp=0 anyway
        const float x = (simp >= 0.f) ? simp : NEG * simp;
        wayacc += lanemask * x * cwv;
    }

#pragma unroll
    for (int m = 32; m > 0; m >>= 1) wayacc += __shfl_xor(wayacc, m, 64);
    if (lane == 0) fin[wid] = wayacc;
    __syncthreads();
    if (tid == 0)
        out[(size_t)b * WAY + w] = fin[0] + fin[1] + fin[2] + fin[3] + cb[0];
}

// ---------------------------------------------------------------------------
extern "C" void kernel_launch(void* const* d_in, const int* in_sizes, int n_in,
                              void* d_out, int out_size, void* d_ws, size_t ws_size,
                              hipStream_t stream) {
    const float* q   = (const float*)d_in[0];   // (8,75,64,21,21)
    const float* sup = (const float*)d_in[1];   // (8,25,64,21,21)
    const float* cw  = (const float*)d_in[2];   // (441,)
    const float* cb  = (const float*)d_in[3];   // (1,)
    float* out = (float*)d_out;                  // (8,75,5)

    char* ws = (char*)d_ws;
    float* pG = (float*)ws;                                    //  6,553,600 B
    float* pS = (float*)(ws + 6553600);                        //    102,400 B
    unsigned short* Wh = (unsigned short*)(ws + 6656000);      //    327,680 B
    unsigned short* Wl = (unsigned short*)(ws + 6983680);      //    327,680 B
    unsigned short* Sh = (unsigned short*)(ws + 7311360);      // 34,406,400 B
    unsigned short* Sl = (unsigned short*)(ws + 41717760);     // 34,406,400 B
    // total 76,124,160 B

    k_prep<<<1000, 256, 0, stream>>>(sup, q, pG, pS, Sh, Sl);
    k_finalize<<<TT * WAY * 8, 256, 0, stream>>>(pG, pS, Wh, Wl);
    k_sim<<<TT * WQ * WAY, 256, 0, stream>>>(Sh, Sl, Wh, Wl, cw, cb, out);
}

// Round 11
// 219.955 us; speedup vs baseline: 1.4887x; 1.4887x over previous
//
#include <hip/hip_runtime.h>

// Problem constants
#define TT 8
#define WQ 75
#define CC 64
#define HW 441
#define WAY 5
#define SHOT 5
#define NSAMP 2205     // SHOT*HW
#define NEG 0.2f
#define PPAD 448       // 28 tiles of 16 positions

typedef __attribute__((ext_vector_type(8))) short bf16x8;
typedef __attribute__((ext_vector_type(4))) float f32x4;

__device__ inline unsigned short f2bf(float f) {
    unsigned u = __float_as_uint(f);
    u += 0x7FFFu + ((u >> 16) & 1u);
    return (unsigned short)(u >> 16);
}
__device__ inline float bf2f(unsigned us) {
    return __uint_as_float((us & 0xFFFFu) << 16);
}

// ---------------------------------------------------------------------------
// k_prep: role-branched.
//  blocks 0..399   : partial second moment G = X X^T + column sums (verified)
//  blocks 400..999 : per-(t,qi) mean -> centered Q -> bf16 hi/lo split S in
//                    FRAGMENT-LINEAR layout: addr(shorts) =
//                    (b*28+tile)*1024 + ks*512 + lane*8,  lane = l16*16+lm16,
//                    holding S[c = ks*32+8*l16+j][p = tile*16+lm16], j=0..7.
//                    (k_sim then loads B-frags as ONE contiguous 1KB/wave txn)
// ---------------------------------------------------------------------------
__global__ __launch_bounds__(256) void k_prep(const float* __restrict__ sup,
                                              const float* __restrict__ Q,
                                              float* __restrict__ pG,
                                              float* __restrict__ pS,
                                              unsigned short* __restrict__ Sh,
                                              unsigned short* __restrict__ Sl) {
    const int tid = threadIdx.x;

    if (blockIdx.x < 400) {
        // ---------------- partial covariance role ----------------
        const int blk = blockIdx.x;
        const int half = blk & 1;
        const int b = blk >> 1;                  // t*25 + s
        const float* __restrict__ X = sup + (size_t)b * CC * HW;
        __shared__ float lds[32 * 68];
        const int i = tid & 15;
        const int j = tid >> 4;
        const int c0 = half * 7, c1 = c0 + 7;

        float acc[4][4];
#pragma unroll
        for (int a = 0; a < 4; ++a)
#pragma unroll
            for (int bb = 0; bb < 4; ++bb) acc[a][bb] = 0.f;
        float cs = 0.f;

        float ld[8];
#pragma unroll
        for (int k = 0; k < 8; ++k) {
            const int e = tid + k * 256;
            const int r = e >> 5, pp = e & 31;
            const int p = c0 * 32 + pp;
            ld[k] = (p < HW) ? X[r * HW + p] : 0.f;
        }

        for (int chunk = c0; chunk < c1; ++chunk) {
            __syncthreads();
#pragma unroll
            for (int k = 0; k < 8; ++k) {
                const int e = tid + k * 256;
                const int r = e >> 5, pp = e & 31;
                lds[pp * 68 + r] = ld[k];
            }
            float ld2[8];
            if (chunk + 1 < c1) {
                const int p0 = (chunk + 1) * 32;
#pragma unroll
                for (int k = 0; k < 8; ++k) {
                    const int e = tid + k * 256;
                    const int r = e >> 5, pp = e & 31;
                    const int p = p0 + pp;
                    ld2[k] = (p < HW) ? X[r * HW + p] : 0.f;
                }
            } else {
#pragma unroll
                for (int k = 0; k < 8; ++k) ld2[k] = 0.f;
            }
            __syncthreads();
#pragma unroll 4
            for (int pp = 0; pp < 32; ++pp) {
                const float* row = &lds[pp * 68];
                const float a0 = row[4 * i + 0], a1 = row[4 * i + 1],
                            a2 = row[4 * i + 2], a3 = row[4 * i + 3];
                const float b0 = row[4 * j + 0], b1 = row[4 * j + 1],
                            b2 = row[4 * j + 2], b3 = row[4 * j + 3];
                acc[0][0] += a0 * b0; acc[0][1] += a0 * b1; acc[0][2] += a0 * b2; acc[0][3] += a0 * b3;
                acc[1][0] += a1 * b0; acc[1][1] += a1 * b1; acc[1][2] += a1 * b2; acc[1][3] += a1 * b3;
                acc[2][0] += a2 * b0; acc[2][1] += a2 * b1; acc[2][2] += a2 * b2; acc[2][3] += a2 * b3;
                acc[3][0] += a3 * b0; acc[3][1] += a3 * b1; acc[3][2] += a3 * b2; acc[3][3] += a3 * b3;
            }
            if (tid < CC) {
#pragma unroll 8
                for (int pp = 0; pp < 32; ++pp) cs += lds[pp * 68 + tid];
            }
#pragma unroll
            for (int k = 0; k < 8; ++k) ld[k] = ld2[k];
        }

        float* __restrict__ G = pG + (size_t)blk * 4096;
#pragma unroll
        for (int a = 0; a < 4; ++a)
#pragma unroll
            for (int bb = 0; bb < 4; ++bb)
                G[(4 * i + a) * 64 + (4 * j + bb)] = acc[a][bb];
        if (tid < CC) pS[blk * 64 + tid] = cs;
    } else {
        // ---------------- center + split role (frag-linear store) ----------
        const int b = blockIdx.x - 400;          // t*75 + qi
        const float* __restrict__ Qb = Q + (size_t)b * CC * HW;
        __shared__ float part[CC][4];
        __shared__ float muL[CC];

        {
            const int c = tid >> 2, qtr = tid & 3;
            float s = 0.f;
            for (int p = qtr * 4; p + 3 < HW; p += 16) {
                const float4 v = *(const float4*)(Qb + (size_t)c * HW + p);
                s += (v.x + v.y) + (v.z + v.w);
            }
            if (qtr == 0) s += Qb[(size_t)c * HW + (HW - 1)];   // element 440
            part[c][qtr] = s;
        }
        __syncthreads();
        if (tid < CC)
            muL[tid] = (part[tid][0] + part[tid][1] + part[tid][2] + part[tid][3]) * (1.f / HW);
        __syncthreads();

        // thread p = tid (+256); 448 slots total
        for (int pi = 0; pi < 2; ++pi) {
            const int p = tid + pi * 256;
            if (p >= PPAD) continue;
            const bool pv = (p < HW);
            const int tt = p >> 4;
            const int lm16 = p & 15;
            const size_t tbase = (size_t)(b * 28 + tt) * 1024;
#pragma unroll
            for (int o = 0; o < 8; ++o) {        // o = ks*4 + l16
                unsigned hp[4], lp[4];
#pragma unroll
                for (int jj = 0; jj < 4; ++jj) {
                    const int cA = o * 8 + jj * 2;
                    const float v0 = pv ? (Qb[(size_t)cA * HW + p] - muL[cA]) : 0.f;
                    const float v1 = pv ? (Qb[(size_t)(cA + 1) * HW + p] - muL[cA + 1]) : 0.f;
                    const unsigned short h0 = f2bf(v0), h1 = f2bf(v1);
                    const unsigned short l0 = f2bf(v0 - bf2f(h0));
                    const unsigned short l1 = f2bf(v1 - bf2f(h1));
                    hp[jj] = (unsigned)h0 | ((unsigned)h1 << 16);
                    lp[jj] = (unsigned)l0 | ((unsigned)l1 << 16);
                }
                const size_t addr = tbase + (size_t)(o >> 2) * 512 + (o & 3) * 128 + lm16 * 8;
                *(uint4*)(Sh + addr) = make_uint4(hp[0], hp[1], hp[2], hp[3]);
                *(uint4*)(Sl + addr) = make_uint4(lp[0], lp[1], lp[2], lp[3]);
            }
        }
    }
}

// ---------------------------------------------------------------------------
// k_finalize: reduce 10 partials -> covariance -> bf16 hi/lo W (row-major).
// 320 blocks, 256 threads, 2 idx each. (verified, unchanged)
// ---------------------------------------------------------------------------
__global__ __launch_bounds__(256) void k_finalize(const float* __restrict__ pG,
                                                  const float* __restrict__ pS,
                                                  unsigned short* __restrict__ Wh,
                                                  unsigned short* __restrict__ Wl) {
    const int blk = blockIdx.x;
    const int b = blk >> 3;                      // t*5 + way
    const int chunk = blk & 7;
    const int t = b / WAY, way = b % WAY;
    const int s0 = (t * 25 + way * SHOT) * 2;

#pragma unroll
    for (int it = 0; it < 2; ++it) {
        const int idx = chunk * 512 + it * 256 + threadIdx.x;
        const int c = idx >> 6, d = idx & 63;
        float g = 0.f, Sc = 0.f, Sd = 0.f;
#pragma unroll
        for (int s = 0; s < SHOT * 2; ++s) {
            g  += pG[(size_t)(s0 + s) * 4096 + idx];
            Sc += pS[(s0 + s) * 64 + c];
            Sd += pS[(s0 + s) * 64 + d];
        }
        const float cov = (g - Sc * Sd * (1.f / NSAMP)) * (1.f / (HW - 1));
        const unsigned short hi = f2bf(cov);
        const unsigned short lo = f2bf(cov - bf2f(hi));
        Wh[(size_t)b * 4096 + idx] = hi;
        Wl[(size_t)b * 4096 + idx] = lo;
    }
}

// ---------------------------------------------------------------------------
// k_sim v8: one (t,qi,way) per block, 4 waves, 7 tiles/wave.
// B-frags: ONE contiguous 1KB/wave load per (ks, hi/lo) from frag-linear S.
// Epilogue: reconstruct s=hi+lo in-reg, exchange via wave-private LDS
// [c][17] (2-way write / <=4-way read conflicts), dot with acc in C/D order —
// bit-identical accumulation order to the verified v7.
// ---------------------------------------------------------------------------
__global__ __launch_bounds__(256) void k_sim(const unsigned short* __restrict__ Sh,
                                             const unsigned short* __restrict__ Sl,
                                             const unsigned short* __restrict__ Wh,
                                             const unsigned short* __restrict__ Wl,
                                             const float* __restrict__ cw,
                                             const float* __restrict__ cb,
                                             float* __restrict__ out) {
    const int gid = blockIdx.x;                  // 0..2999
    const int grp = gid / 40, rem = gid % 40;
    const int w = rem >> 3;                      // 0..4
    const int b = grp * 8 + (rem & 7);           // t*75 + qi
    const int t = b / WQ;
    const int tid = threadIdx.x;
    const int lane = tid & 63;
    const int wid = tid >> 6;                    // 0..3
    const int lm16 = lane & 15;
    const int l16 = lane >> 4;                   // 0..3
    const float lanemask = (l16 == 0) ? 1.f : 0.f;

    __shared__ float sl[4][CC][17];              // wave-private s-tile [c][p]
    __shared__ float fin[4];

    // A-frags: W[row = rt*16 + lm16][k = ks*32 + 8*l16 + j]  (row-major W)
    const unsigned short* __restrict__ Wm_h = Wh + (size_t)(t * WAY + w) * 4096;
    const unsigned short* __restrict__ Wm_l = Wl + (size_t)(t * WAY + w) * 4096;
    bf16x8 ah[4][2], al[4][2];
#pragma unroll
    for (int rt = 0; rt < 4; ++rt)
#pragma unroll
        for (int ks = 0; ks < 2; ++ks) {
            const size_t off = (size_t)(rt * 16 + lm16) * 64 + ks * 32 + 8 * l16;
            ah[rt][ks] = __builtin_bit_cast(bf16x8, *(const uint4*)(Wm_h + off));
            al[rt][ks] = __builtin_bit_cast(bf16x8, *(const uint4*)(Wm_l + off));
        }

    float wayacc = 0.f;
#pragma unroll 1
    for (int k = 0; k < 7; ++k) {
        const int tt = wid + 4 * k;              // tile 0..27
        const size_t tbase = (size_t)(b * 28 + tt) * 1024;

        // B-frags: contiguous lane*16B loads (coalesced 1KB/wave)
        bf16x8 bh[2], bl[2];
#pragma unroll
        for (int ks = 0; ks < 2; ++ks) {
            const size_t off = tbase + (size_t)ks * 512 + lane * 8;
            bh[ks] = __builtin_bit_cast(bf16x8, *(const uint4*)(Sh + off));
            bl[ks] = __builtin_bit_cast(bf16x8, *(const uint4*)(Sl + off));
        }

        f32x4 acc[4];
#pragma unroll
        for (int rt = 0; rt < 4; ++rt) acc[rt] = (f32x4){0.f, 0.f, 0.f, 0.f};

#pragma unroll
        for (int rt = 0; rt < 4; ++rt)
#pragma unroll
            for (int ks = 0; ks < 2; ++ks) {
                acc[rt] = __builtin_amdgcn_mfma_f32_16x16x32_bf16(ah[rt][ks], bh[ks], acc[rt], 0, 0, 0);
                acc[rt] = __builtin_amdgcn_mfma_f32_16x16x32_bf16(ah[rt][ks], bl[ks], acc[rt], 0, 0, 0);
                acc[rt] = __builtin_amdgcn_mfma_f32_16x16x32_bf16(al[rt][ks], bh[ks], acc[rt], 0, 0, 0);
            }

        // reconstruct s = hi+lo for this lane's 16 c's, park in LDS [c][p]
#pragma unroll
        for (int ks = 0; ks < 2; ++ks) {
            const unsigned* hu = (const unsigned*)&bh[ks];
            const unsigned* lu = (const unsigned*)&bl[ks];
#pragma unroll
            for (int jj = 0; jj < 4; ++jj) {
                const int c0 = ks * 32 + 8 * l16 + jj * 2;
                sl[wid][c0][lm16]     = bf2f(hu[jj]) + bf2f(lu[jj]);
                sl[wid][c0 + 1][lm16] = bf2f(hu[jj] >> 16) + bf2f(lu[jj] >> 16);
            }
        }
        __builtin_amdgcn_wave_barrier();

        // epilogue: simp = sum over lane's 16 c's (C/D layout) of acc * s
        float simp = 0.f;
#pragma unroll
        for (int rt = 0; rt < 4; ++rt) {
            const int c0 = rt * 16 + l16 * 4;
            simp += acc[rt][0] * sl[wid][c0 + 0][lm16];
            simp += acc[rt][1] * sl[wid][c0 + 1][lm16];
            simp += acc[rt][2] * sl[wid][c0 + 2][lm16];
            simp += acc[rt][3] * sl[wid][c0 + 3][lm16];
        }
        __builtin_amdgcn_wave_barrier();         // protect LDS before next tile
        simp += __shfl_xor(simp, 16, 64);
        simp += __shfl_xor(simp, 32, 64);

        const int p_l = tt * 16 + lm16;
        const float cwv = (p_l < HW) ? cw[p_l] : 0.f;   // padded p: simp=0 anyway
        const float x = (simp >= 0.f) ? simp : NEG * simp;
        wayacc += lanemask * x * cwv;
    }

#pragma unroll
    for (int m = 32; m > 0; m >>= 1) wayacc += __shfl_xor(wayacc, m, 64);
    if (lane == 0) fin[wid] = wayacc;
    __syncthreads();
    if (tid == 0)
        out[(size_t)b * WAY + w] = fin[0] + fin[1] + fin[2] + fin[3] + cb[0];
}

// ---------------------------------------------------------------------------
extern "C" void kernel_launch(void* const* d_in, const int* in_sizes, int n_in,
                              void* d_out, int out_size, void* d_ws, size_t ws_size,
                              hipStream_t stream) {
    const float* q   = (const float*)d_in[0];   // (8,75,64,21,21)
    const float* sup = (const float*)d_in[1];   // (8,25,64,21,21)
    const float* cw  = (const float*)d_in[2];   // (441,)
    const float* cb  = (const float*)d_in[3];   // (1,)
    float* out = (float*)d_out;                  // (8,75,5)

    char* ws = (char*)d_ws;
    float* pG = (float*)ws;                                    //  6,553,600 B
    float* pS = (float*)(ws + 6553600);                        //    102,400 B
    unsigned short* Wh = (unsigned short*)(ws + 6656000);      //    327,680 B
    unsigned short* Wl = (unsigned short*)(ws + 6983680);      //    327,680 B
    unsigned short* Sh = (unsigned short*)(ws + 7311360);      // 34,406,400 B
    unsigned short* Sl = (unsigned short*)(ws + 41717760);     // 34,406,400 B
    // total 76,124,160 B (same footprint as verified R7 layout)

    k_prep<<<1000, 256, 0, stream>>>(sup, q, pG, pS, Sh, Sl);
    k_finalize<<<TT * WAY * 8, 256, 0, stream>>>(pG, pS, Wh, Wl);
    k_sim<<<TT * WQ * WAY, 256, 0, stream>>>(Sh, Sl, Wh, Wl, cw, cb, out);
}

// Round 12
// 202.855 us; speedup vs baseline: 1.6142x; 1.0843x over previous
//
#include <hip/hip_runtime.h>

// Problem constants
#define TT 8
#define WQ 75
#define CC 64
#define HW 441
#define WAY 5
#define SHOT 5
#define NSAMP 2205     // SHOT*HW
#define NEG 0.2f
#define PPAD 448       // 28 tiles of 16 positions

typedef __attribute__((ext_vector_type(8))) short bf16x8;
typedef __attribute__((ext_vector_type(4))) float f32x4;

__device__ inline unsigned short f2bf(float f) {
    unsigned u = __float_as_uint(f);
    u += 0x7FFFu + ((u >> 16) & 1u);
    return (unsigned short)(u >> 16);
}
__device__ inline float bf2f(unsigned us) {
    return __uint_as_float((us & 0xFFFFu) << 16);
}

// ---------------------------------------------------------------------------
// k_prep: role-branched.
//  blocks 0..399    : partial second moment G = X X^T + column sums (verified)
//  blocks 400..1599 : center+split, one block per (t*75+qi, channel-half).
//                     Block handles 32 channels: mean over own rows (float4
//                     along p), then bf16 hi/lo split into FRAGMENT-LINEAR S:
//                     addr(shorts) = (b*28+tile)*1024 + ks*512 + l16*128 +
//                     jj*... (o = ks*4+l16, c = o*8+jj*2), ks == half.
// ---------------------------------------------------------------------------
__global__ __launch_bounds__(256) void k_prep(const float* __restrict__ sup,
                                              const float* __restrict__ Q,
                                              float* __restrict__ pG,
                                              float* __restrict__ pS,
                                              unsigned short* __restrict__ Sh,
                                              unsigned short* __restrict__ Sl) {
    const int tid = threadIdx.x;

    if (blockIdx.x < 400) {
        // ---------------- partial covariance role ----------------
        const int blk = blockIdx.x;
        const int half = blk & 1;
        const int b = blk >> 1;                  // t*25 + s
        const float* __restrict__ X = sup + (size_t)b * CC * HW;
        __shared__ float lds[32 * 68];
        const int i = tid & 15;
        const int j = tid >> 4;
        const int c0 = half * 7, c1 = c0 + 7;

        float acc[4][4];
#pragma unroll
        for (int a = 0; a < 4; ++a)
#pragma unroll
            for (int bb = 0; bb < 4; ++bb) acc[a][bb] = 0.f;
        float cs = 0.f;

        float ld[8];
#pragma unroll
        for (int k = 0; k < 8; ++k) {
            const int e = tid + k * 256;
            const int r = e >> 5, pp = e & 31;
            const int p = c0 * 32 + pp;
            ld[k] = (p < HW) ? X[r * HW + p] : 0.f;
        }

        for (int chunk = c0; chunk < c1; ++chunk) {
            __syncthreads();
#pragma unroll
            for (int k = 0; k < 8; ++k) {
                const int e = tid + k * 256;
                const int r = e >> 5, pp = e & 31;
                lds[pp * 68 + r] = ld[k];
            }
            float ld2[8];
            if (chunk + 1 < c1) {
                const int p0 = (chunk + 1) * 32;
#pragma unroll
                for (int k = 0; k < 8; ++k) {
                    const int e = tid + k * 256;
                    const int r = e >> 5, pp = e & 31;
                    const int p = p0 + pp;
                    ld2[k] = (p < HW) ? X[r * HW + p] : 0.f;
                }
            } else {
#pragma unroll
                for (int k = 0; k < 8; ++k) ld2[k] = 0.f;
            }
            __syncthreads();
#pragma unroll 4
            for (int pp = 0; pp < 32; ++pp) {
                const float* row = &lds[pp * 68];
                const float a0 = row[4 * i + 0], a1 = row[4 * i + 1],
                            a2 = row[4 * i + 2], a3 = row[4 * i + 3];
                const float b0 = row[4 * j + 0], b1 = row[4 * j + 1],
                            b2 = row[4 * j + 2], b3 = row[4 * j + 3];
                acc[0][0] += a0 * b0; acc[0][1] += a0 * b1; acc[0][2] += a0 * b2; acc[0][3] += a0 * b3;
                acc[1][0] += a1 * b0; acc[1][1] += a1 * b1; acc[1][2] += a1 * b2; acc[1][3] += a1 * b3;
                acc[2][0] += a2 * b0; acc[2][1] += a2 * b1; acc[2][2] += a2 * b2; acc[2][3] += a2 * b3;
                acc[3][0] += a3 * b0; acc[3][1] += a3 * b1; acc[3][2] += a3 * b2; acc[3][3] += a3 * b3;
            }
            if (tid < CC) {
#pragma unroll 8
                for (int pp = 0; pp < 32; ++pp) cs += lds[pp * 68 + tid];
            }
#pragma unroll
            for (int k = 0; k < 8; ++k) ld[k] = ld2[k];
        }

        float* __restrict__ G = pG + (size_t)blk * 4096;
#pragma unroll
        for (int a = 0; a < 4; ++a)
#pragma unroll
            for (int bb = 0; bb < 4; ++bb)
                G[(4 * i + a) * 64 + (4 * j + bb)] = acc[a][bb];
        if (tid < CC) pS[blk * 64 + tid] = cs;
    } else {
        // ------------- center + split role (per channel-half) -------------
        const int idx = blockIdx.x - 400;        // 0..1199
        const int b = idx >> 1;                  // t*75 + qi
        const int half = idx & 1;                // ks half: channels [half*32, +32)
        const float* __restrict__ Qb = Q + (size_t)b * CC * HW;
        __shared__ float part[32][8];
        __shared__ float muL[32];

        // mean for this block's 32 channels (float4 along p)
        {
            const int cl = tid >> 3;             // 0..31
            const int c = half * 32 + cl;
            const int oc = tid & 7;
            float s = 0.f;
            for (int p = oc * 4; p + 3 < HW; p += 32) {
                const float4 v = *(const float4*)(Qb + (size_t)c * HW + p);
                s += (v.x + v.y) + (v.z + v.w);
            }
            if (oc == 0) s += Qb[(size_t)c * HW + (HW - 1)];   // element 440
            part[cl][oc] = s;
        }
        __syncthreads();
        if (tid < 32) {
            float s = 0.f;
#pragma unroll
            for (int o = 0; o < 8; ++o) s += part[tid][o];
            muL[tid] = s * (1.f / HW);
        }
        __syncthreads();

        // split: thread p = tid (+256), 4 o-iterations (ks = half fixed)
        for (int pi = 0; pi < 2; ++pi) {
            const int p = tid + pi * 256;
            if (p >= PPAD) continue;
            const bool pv = (p < HW);
            const int tt = p >> 4;
            const int lm16 = p & 15;
            const size_t tbase = (size_t)(b * 28 + tt) * 1024 + (size_t)half * 512;
#pragma unroll
            for (int o4 = 0; o4 < 4; ++o4) {     // l16 = o4
                unsigned hp[4], lp[4];
#pragma unroll
                for (int jj = 0; jj < 4; ++jj) {
                    const int cA = half * 32 + o4 * 8 + jj * 2;   // global channel
                    const int cl = cA - half * 32;                 // local 0..31
                    const float v0 = pv ? (Qb[(size_t)cA * HW + p] - muL[cl]) : 0.f;
                    const float v1 = pv ? (Qb[(size_t)(cA + 1) * HW + p] - muL[cl + 1]) : 0.f;
                    const unsigned short h0 = f2bf(v0), h1 = f2bf(v1);
                    const unsigned short l0 = f2bf(v0 - bf2f(h0));
                    const unsigned short l1 = f2bf(v1 - bf2f(h1));
                    hp[jj] = (unsigned)h0 | ((unsigned)h1 << 16);
                    lp[jj] = (unsigned)l0 | ((unsigned)l1 << 16);
                }
                const size_t addr = tbase + (size_t)o4 * 128 + lm16 * 8;
                *(uint4*)(Sh + addr) = make_uint4(hp[0], hp[1], hp[2], hp[3]);
                *(uint4*)(Sl + addr) = make_uint4(lp[0], lp[1], lp[2], lp[3]);
            }
        }
    }
}

// ---------------------------------------------------------------------------
// k_finalize: reduce 10 partials -> covariance -> bf16 hi/lo W (row-major).
// 320 blocks, 256 threads, 2 idx each. (verified, unchanged)
// ---------------------------------------------------------------------------
__global__ __launch_bounds__(256) void k_finalize(const float* __restrict__ pG,
                                                  const float* __restrict__ pS,
                                                  unsigned short* __restrict__ Wh,
                                                  unsigned short* __restrict__ Wl) {
    const int blk = blockIdx.x;
    const int b = blk >> 3;                      // t*5 + way
    const int chunk = blk & 7;
    const int t = b / WAY, way = b % WAY;
    const int s0 = (t * 25 + way * SHOT) * 2;

#pragma unroll
    for (int it = 0; it < 2; ++it) {
        const int idx = chunk * 512 + it * 256 + threadIdx.x;
        const int c = idx >> 6, d = idx & 63;
        float g = 0.f, Sc = 0.f, Sd = 0.f;
#pragma unroll
        for (int s = 0; s < SHOT * 2; ++s) {
            g  += pG[(size_t)(s0 + s) * 4096 + idx];
            Sc += pS[(s0 + s) * 64 + c];
            Sd += pS[(s0 + s) * 64 + d];
        }
        const float cov = (g - Sc * Sd * (1.f / NSAMP)) * (1.f / (HW - 1));
        const unsigned short hi = f2bf(cov);
        const unsigned short lo = f2bf(cov - bf2f(hi));
        Wh[(size_t)b * 4096 + idx] = hi;
        Wl[(size_t)b * 4096 + idx] = lo;
    }
}

// ---------------------------------------------------------------------------
// k_sim v8: one (t,qi,way) per block, 4 waves, 7 tiles/wave.
// B-frags: ONE contiguous 1KB/wave load per (ks, hi/lo) from frag-linear S.
// Epilogue via wave-private LDS exchange. (verified absmax 0.0, unchanged)
// ---------------------------------------------------------------------------
__global__ __launch_bounds__(256) void k_sim(const unsigned short* __restrict__ Sh,
                                             const unsigned short* __restrict__ Sl,
                                             const unsigned short* __restrict__ Wh,
                                             const unsigned short* __restrict__ Wl,
                                             const float* __restrict__ cw,
                                             const float* __restrict__ cb,
                                             float* __restrict__ out) {
    const int gid = blockIdx.x;                  // 0..2999
    const int grp = gid / 40, rem = gid % 40;
    const int w = rem >> 3;                      // 0..4
    const int b = grp * 8 + (rem & 7);           // t*75 + qi
    const int t = b / WQ;
    const int tid = threadIdx.x;
    const int lane = tid & 63;
    const int wid = tid >> 6;                    // 0..3
    const int lm16 = lane & 15;
    const int l16 = lane >> 4;                   // 0..3
    const float lanemask = (l16 == 0) ? 1.f : 0.f;

    __shared__ float sl[4][CC][17];              // wave-private s-tile [c][p]
    __shared__ float fin[4];

    // A-frags: W[row = rt*16 + lm16][k = ks*32 + 8*l16 + j]  (row-major W)
    const unsigned short* __restrict__ Wm_h = Wh + (size_t)(t * WAY + w) * 4096;
    const unsigned short* __restrict__ Wm_l = Wl + (size_t)(t * WAY + w) * 4096;
    bf16x8 ah[4][2], al[4][2];
#pragma unroll
    for (int rt = 0; rt < 4; ++rt)
#pragma unroll
        for (int ks = 0; ks < 2; ++ks) {
            const size_t off = (size_t)(rt * 16 + lm16) * 64 + ks * 32 + 8 * l16;
            ah[rt][ks] = __builtin_bit_cast(bf16x8, *(const uint4*)(Wm_h + off));
            al[rt][ks] = __builtin_bit_cast(bf16x8, *(const uint4*)(Wm_l + off));
        }

    float wayacc = 0.f;
#pragma unroll 1
    for (int k = 0; k < 7; ++k) {
        const int tt = wid + 4 * k;              // tile 0..27
        const size_t tbase = (size_t)(b * 28 + tt) * 1024;

        // B-frags: contiguous lane*16B loads (coalesced 1KB/wave)
        bf16x8 bh[2], bl[2];
#pragma unroll
        for (int ks = 0; ks < 2; ++ks) {
            const size_t off = tbase + (size_t)ks * 512 + lane * 8;
            bh[ks] = __builtin_bit_cast(bf16x8, *(const uint4*)(Sh + off));
            bl[ks] = __builtin_bit_cast(bf16x8, *(const uint4*)(Sl + off));
        }

        f32x4 acc[4];
#pragma unroll
        for (int rt = 0; rt < 4; ++rt) acc[rt] = (f32x4){0.f, 0.f, 0.f, 0.f};

#pragma unroll
        for (int rt = 0; rt < 4; ++rt)
#pragma unroll
            for (int ks = 0; ks < 2; ++ks) {
                acc[rt] = __builtin_amdgcn_mfma_f32_16x16x32_bf16(ah[rt][ks], bh[ks], acc[rt], 0, 0, 0);
                acc[rt] = __builtin_amdgcn_mfma_f32_16x16x32_bf16(ah[rt][ks], bl[ks], acc[rt], 0, 0, 0);
                acc[rt] = __builtin_amdgcn_mfma_f32_16x16x32_bf16(al[rt][ks], bh[ks], acc[rt], 0, 0, 0);
            }

        // reconstruct s = hi+lo for this lane's 16 c's, park in LDS [c][p]
#pragma unroll
        for (int ks = 0; ks < 2; ++ks) {
            const unsigned* hu = (const unsigned*)&bh[ks];
            const unsigned* lu = (const unsigned*)&bl[ks];
#pragma unroll
            for (int jj = 0; jj < 4; ++jj) {
                const int c0 = ks * 32 + 8 * l16 + jj * 2;
                sl[wid][c0][lm16]     = bf2f(hu[jj]) + bf2f(lu[jj]);
                sl[wid][c0 + 1][lm16] = bf2f(hu[jj] >> 16) + bf2f(lu[jj] >> 16);
            }
        }
        __builtin_amdgcn_wave_barrier();

        // epilogue: simp = sum over lane's 16 c's (C/D layout) of acc * s
        float simp = 0.f;
#pragma unroll
        for (int rt = 0; rt < 4; ++rt) {
            const int c0 = rt * 16 + l16 * 4;
            simp += acc[rt][0] * sl[wid][c0 + 0][lm16];
            simp += acc[rt][1] * sl[wid][c0 + 1][lm16];
            simp += acc[rt][2] * sl[wid][c0 + 2][lm16];
            simp += acc[rt][3] * sl[wid][c0 + 3][lm16];
        }
        __builtin_amdgcn_wave_barrier();         // protect LDS before next tile
        simp += __shfl_xor(simp, 16, 64);
        simp += __shfl_xor(simp, 32, 64);

        const int p_l = tt * 16 + lm16;
        const float cwv = (p_l < HW) ? cw[p_l] : 0.f;   // padded p: simp=0 anyway
        const float x = (simp >= 0.f) ? simp : NEG * simp;
        wayacc += lanemask * x * cwv;
    }

#pragma unroll
    for (int m = 32; m > 0; m >>= 1) wayacc += __shfl_xor(wayacc, m, 64);
    if (lane == 0) fin[wid] = wayacc;
    __syncthreads();
    if (tid == 0)
        out[(size_t)b * WAY + w] = fin[0] + fin[1] + fin[2] + fin[3] + cb[0];
}

// ---------------------------------------------------------------------------
extern "C" void kernel_launch(void* const* d_in, const int* in_sizes, int n_in,
                              void* d_out, int out_size, void* d_ws, size_t ws_size,
                              hipStream_t stream) {
    const float* q   = (const float*)d_in[0];   // (8,75,64,21,21)
    const float* sup = (const float*)d_in[1];   // (8,25,64,21,21)
    const float* cw  = (const float*)d_in[2];   // (441,)
    const float* cb  = (const float*)d_in[3];   // (1,)
    float* out = (float*)d_out;                  // (8,75,5)

    char* ws = (char*)d_ws;
    float* pG = (float*)ws;                                    //  6,553,600 B
    float* pS = (float*)(ws + 6553600);                        //    102,400 B
    unsigned short* Wh = (unsigned short*)(ws + 6656000);      //    327,680 B
    unsigned short* Wl = (unsigned short*)(ws + 6983680);      //    327,680 B
    unsigned short* Sh = (unsigned short*)(ws + 7311360);      // 34,406,400 B
    unsigned short* Sl = (unsigned short*)(ws + 41717760);     // 34,406,400 B
    // total 76,124,160 B

    k_prep<<<400 + 1200, 256, 0, stream>>>(sup, q, pG, pS, Sh, Sl);
    k_finalize<<<TT * WAY * 8, 256, 0, stream>>>(pG, pS, Wh, Wl);
    k_sim<<<TT * WQ * WAY, 256, 0, stream>>>(Sh, Sl, Wh, Wl, cw, cb, out);
}